// Round 6
// baseline (1575.643 us; speedup 1.0000x reference)
//
#include <hip/hip_runtime.h>
#include <hip/hip_bf16.h>

typedef __hip_bfloat16 bf16;

__device__ __forceinline__ float bf2f(bf16 v) { return __bfloat162float(v); }
__device__ __forceinline__ float lo16(unsigned u) { return __uint_as_float((u & 0xffffu) << 16); }
__device__ __forceinline__ float hi16(unsigned u) { return __uint_as_float(u & 0xffff0000u); }
__device__ __forceinline__ unsigned short f2bfbits(float f) {
    return (unsigned short)(__hip_bfloat16_raw(__float2bfloat16(f)).x);
}
__device__ __forceinline__ unsigned pack2(float a, float b) {
    return (unsigned)f2bfbits(a) | ((unsigned)f2bfbits(b) << 16);
}

// dtype-dispatching loads (flag-driven, uniform branch)
__device__ __forceinline__ float ldf(const void* p, size_t i, bool isbf) {
    return isbf ? bf2f(((const bf16*)p)[i]) : ((const float*)p)[i];
}
__device__ __forceinline__ int ldi(const void* p, size_t i, bool is64) {
    return is64 ? (int)((const long long*)p)[i] : ((const int*)p)[i];
}
__device__ __forceinline__ float sane(float v) {
    return (v == v && fabsf(v) < 1e30f) ? v : 0.f;
}

// ---------------- dtype detection ----------------
__global__ void detect(const unsigned* __restrict__ w1w, const unsigned* __restrict__ eiw,
                       int* __restrict__ flags) {
    __shared__ int cnt[2];
    if (threadIdx.x < 2) cnt[threadIdx.x] = 0;
    __syncthreads();
    int c0 = 0;
    for (int i = threadIdx.x; i < 4096; i += 256) {
        unsigned u = w1w[i];
        unsigned e0 = (u >> 7) & 0xFFu, e1 = (u >> 23) & 0xFFu;
        if (e0 <= 125u && e1 <= 125u) c0++;
    }
    int c1 = 0;
    for (int i = threadIdx.x; i < 2048; i += 256)
        if (eiw[2 * i + 1] == 0u) c1++;
    atomicAdd(&cnt[0], c0);
    atomicAdd(&cnt[1], c1);
    __syncthreads();
    if (threadIdx.x == 0) {
        flags[0] = (cnt[0] >= 3072) ? 1 : 0;
        flags[1] = (cnt[1] >= 1024) ? 1 : 0;
    }
}

// ---------------- init: deg=1, cnt=0, hist=0 ----------------
__global__ void initk(float* __restrict__ deg, int* __restrict__ cnt,
                      int* __restrict__ hist, int n) {
    int i = blockIdx.x * blockDim.x + threadIdx.x;
    if (i < n) { deg[i] = 1.0f; cnt[i] = 0; }
    if (i < 256) hist[i] = 0;
}

// ---------------- count in-degree + weighted degree ----------------
__global__ void degcnt(const void* __restrict__ ei, const void* __restrict__ w,
                       float* __restrict__ deg, int* __restrict__ cnt,
                       const int* __restrict__ flags, int e, int n) {
    const bool isbf = flags[0] != 0;
    const bool is64 = flags[1] != 0;
    int i = blockIdx.x * blockDim.x + threadIdx.x;
    if (i < e) {
        int c = ldi(ei, (size_t)e + i, is64);
        if ((unsigned)c < (unsigned)n) {
            atomicAdd(&cnt[c], 1);
            unsafeAtomicAdd(&deg[c], sane(ldf(w, i, isbf)));
        }
    }
}

// ---------------- scans ----------------
__global__ __launch_bounds__(1024) void scan1(const int* __restrict__ cnt,
                                              int* __restrict__ rp,
                                              int* __restrict__ bsum, int n) {
    __shared__ int s[1024];
    int gid = blockIdx.x * 1024 + threadIdx.x;
    int v = (gid < n) ? cnt[gid] : 0;
    s[threadIdx.x] = v;
    __syncthreads();
    for (int off = 1; off < 1024; off <<= 1) {
        int t = 0;
        if (threadIdx.x >= off) t = s[threadIdx.x - off];
        __syncthreads();
        if (threadIdx.x >= off) s[threadIdx.x] += t;
        __syncthreads();
    }
    if (gid < n) rp[gid] = s[threadIdx.x] - v;
    if (threadIdx.x == 1023) bsum[blockIdx.x] = s[1023];
}

__global__ __launch_bounds__(1024) void scan2(const int* __restrict__ bsum,
                                              int* __restrict__ bsx, int nb) {
    __shared__ int s[1024];
    int v = (threadIdx.x < nb) ? bsum[threadIdx.x] : 0;
    s[threadIdx.x] = v;
    __syncthreads();
    for (int off = 1; off < 1024; off <<= 1) {
        int t = 0;
        if (threadIdx.x >= off) t = s[threadIdx.x - off];
        __syncthreads();
        if (threadIdx.x >= off) s[threadIdx.x] += t;
        __syncthreads();
    }
    if (threadIdx.x < nb) bsx[threadIdx.x] = s[threadIdx.x] - v;
}

__global__ void scan3(int* __restrict__ rp, int* __restrict__ cursor,
                      const int* __restrict__ bsx, float* __restrict__ deg,
                      int n, int e) {
    int i = blockIdx.x * blockDim.x + threadIdx.x;
    if (i < n) {
        int v = rp[i] + bsx[i >> 10];
        rp[i] = v;
        cursor[i] = v;
        float d = deg[i];
        deg[i] = d > 0.f ? rsqrtf(d) : 0.f;
    }
    if (i == 0) rp[n] = e;
}

// ---------------- fill CSR ----------------
__global__ void fill(const void* __restrict__ ei, const void* __restrict__ w,
                     int* __restrict__ cursor, uint2* __restrict__ epack,
                     const int* __restrict__ flags, int e, int n) {
    const bool isbf = flags[0] != 0;
    const bool is64 = flags[1] != 0;
    int i = blockIdx.x * blockDim.x + threadIdx.x;
    if (i < e) {
        int r = ldi(ei, (size_t)i, is64);
        int c = ldi(ei, (size_t)e + i, is64);
        if ((unsigned)r < (unsigned)n && (unsigned)c < (unsigned)n) {
            float wv = sane(ldf(w, i, isbf));
            int pos = atomicAdd(&cursor[c], 1);
            epack[pos] = make_uint2((unsigned)r, __float_as_uint(wv));
        }
    }
}

// ---------------- degree histogram / scan / counting sort ----------------
__global__ void histk(const int* __restrict__ cnt, int* __restrict__ hist, int n) {
    int i = blockIdx.x * blockDim.x + threadIdx.x;
    if (i < n) atomicAdd(&hist[min(cnt[i], 255)], 1);
}

__global__ void hscan(const int* __restrict__ hist, int* __restrict__ hcur) {
    __shared__ int s[256];
    int v = hist[threadIdx.x];
    s[threadIdx.x] = v;
    __syncthreads();
    for (int off = 1; off < 256; off <<= 1) {
        int t = 0;
        if (threadIdx.x >= off) t = s[threadIdx.x - off];
        __syncthreads();
        if (threadIdx.x >= off) s[threadIdx.x] += t;
        __syncthreads();
    }
    hcur[threadIdx.x] = s[threadIdx.x] - v;  // exclusive
}

__global__ void sortk(const int* __restrict__ cnt, int* __restrict__ hcur,
                      int* __restrict__ order, int n) {
    int i = blockIdx.x * blockDim.x + threadIdx.x;
    if (i < n) {
        int pos = atomicAdd(&hcur[min(cnt[i], 255)], 1);
        order[pos] = i;
    }
}

// ---- layer1 GEMM: G1 = bf16(dinv ⊙ (X @ W1)), rows packed as 32 uints ----
__global__ __launch_bounds__(256) void gemm1(const void* __restrict__ x,
                                             const void* __restrict__ W1,
                                             const float* __restrict__ dinv,
                                             const int* __restrict__ flags,
                                             unsigned* __restrict__ G1, int n) {
    const bool isbf = flags[0] != 0;
    __shared__ float ws[128 * 64];
    for (int i = threadIdx.x; i < 128 * 64; i += 256) ws[i] = ldf(W1, i, isbf);
    __syncthreads();

    const int lane = threadIdx.x & 63;
    const int wid  = (blockIdx.x * 256 + threadIdx.x) >> 6;
    const int nw   = (gridDim.x * 256) >> 6;

    for (int row = wid; row < n; row += nw) {
        const size_t base = (size_t)row * 128;
        const float xa = ldf(x, base + 2 * lane, isbf);
        const float xb = ldf(x, base + 2 * lane + 1, isbf);
        float h = 0.f;
#pragma unroll
        for (int m = 0; m < 64; ++m) {
            h = fmaf(__shfl(xa, m), ws[(2 * m) * 64 + lane], h);
            h = fmaf(__shfl(xb, m), ws[(2 * m + 1) * 64 + lane], h);
        }
        float gv = dinv[row] * h;
        float other = __shfl_xor(gv, 1);
        if ((lane & 1) == 0)
            G1[(size_t)row * 32 + (lane >> 1)] = pack2(gv, other);
    }
}

// ---- gather core: 8 lanes per node, uint4 (16B) per lane, depth-8 pipeline ----
// lane `sub` owns dims [8*sub, 8*sub+8); acc[t] = dim 8*sub+t
__device__ __forceinline__ void gacc8(const int* __restrict__ rp,
                                      const uint2* __restrict__ epack,
                                      const uint4* __restrict__ Gv,
                                      int node, int sub, float acc[8]) {
    uint4 self = Gv[(size_t)node * 8 + sub];
    acc[0] = lo16(self.x); acc[1] = hi16(self.x);
    acc[2] = lo16(self.y); acc[3] = hi16(self.y);
    acc[4] = lo16(self.z); acc[5] = hi16(self.z);
    acc[6] = lo16(self.w); acc[7] = hi16(self.w);

    const int s0 = rp[node], s1 = rp[node + 1];
    for (int base = s0; base < s1; base += 8) {
        int idx = base + sub;
        uint2 ld = (idx < s1) ? epack[idx] : make_uint2((unsigned)node, 0u);
        int rr[8]; float wv[8];
#pragma unroll
        for (int u = 0; u < 8; ++u) {
            rr[u] = __shfl((int)ld.x, u, 8);
            wv[u] = __uint_as_float((unsigned)__shfl((int)ld.y, u, 8));
        }
        uint4 gp[8];
#pragma unroll
        for (int u = 0; u < 8; ++u) gp[u] = Gv[(size_t)rr[u] * 8 + sub];
#pragma unroll
        for (int u = 0; u < 8; ++u) {
            acc[0] = fmaf(wv[u], lo16(gp[u].x), acc[0]);
            acc[1] = fmaf(wv[u], hi16(gp[u].x), acc[1]);
            acc[2] = fmaf(wv[u], lo16(gp[u].y), acc[2]);
            acc[3] = fmaf(wv[u], hi16(gp[u].y), acc[3]);
            acc[4] = fmaf(wv[u], lo16(gp[u].z), acc[4]);
            acc[5] = fmaf(wv[u], hi16(gp[u].z), acc[5]);
            acc[6] = fmaf(wv[u], lo16(gp[u].w), acc[6]);
            acc[7] = fmaf(wv[u], hi16(gp[u].w), acc[7]);
        }
    }
}

// ---- agg1: acc -> relu/bias/dinv -> G2 (packed uint4) ----
__global__ __launch_bounds__(256) void agg1(const int* __restrict__ rp,
                                            const uint2* __restrict__ epack,
                                            const int* __restrict__ order,
                                            const uint4* __restrict__ G1v,
                                            const float* __restrict__ dinv,
                                            const void* __restrict__ b1,
                                            const int* __restrict__ flags,
                                            uint4* __restrict__ G2v, int n) {
    const bool isbf = flags[0] != 0;
    const int sub = threadIdx.x & 7;
    const int g   = (blockIdx.x * 256 + threadIdx.x) >> 3;
    if (g >= n) return;
    const int node = order[g];

    float acc[8];
    gacc8(rp, epack, G1v, node, sub, acc);

    const float dv = dinv[node];
    unsigned o[4];
#pragma unroll
    for (int t = 0; t < 4; ++t) {
        float h0 = dv * acc[2 * t]     + ldf(b1, 8 * sub + 2 * t, isbf);
        float h1 = dv * acc[2 * t + 1] + ldf(b1, 8 * sub + 2 * t + 1, isbf);
        h0 = h0 > 0.f ? h0 : 0.f;
        h1 = h1 > 0.f ? h1 : 0.f;
        o[t] = pack2(dv * h0, dv * h1);
    }
    G2v[(size_t)node * 8 + sub] = make_uint4(o[0], o[1], o[2], o[3]);
}

// ---- agg2: acc -> T = bf16(dinv * acc) (packed uint4) ----
__global__ __launch_bounds__(256) void agg2(const int* __restrict__ rp,
                                            const uint2* __restrict__ epack,
                                            const int* __restrict__ order,
                                            const uint4* __restrict__ G2v,
                                            const float* __restrict__ dinv,
                                            uint4* __restrict__ Tv, int n) {
    const int sub = threadIdx.x & 7;
    const int g   = (blockIdx.x * 256 + threadIdx.x) >> 3;
    if (g >= n) return;
    const int node = order[g];

    float acc[8];
    gacc8(rp, epack, G2v, node, sub, acc);

    const float dv = dinv[node];
    uint4 o;
    o.x = pack2(dv * acc[0], dv * acc[1]);
    o.y = pack2(dv * acc[2], dv * acc[3]);
    o.z = pack2(dv * acc[4], dv * acc[5]);
    o.w = pack2(dv * acc[6], dv * acc[7]);
    Tv[(size_t)node * 8 + sub] = o;
}

// ---- outgemm: out = T @ W2 + b2 (half-wave per node) ----
__global__ __launch_bounds__(256) void outgemm(const unsigned* __restrict__ T,
                                               const void* __restrict__ W2,
                                               const void* __restrict__ b2,
                                               const int* __restrict__ flags,
                                               void* __restrict__ outp, int n) {
    const bool isbf = flags[0] != 0;
    __shared__ float ws[64 * 128];
    for (int i = threadIdx.x; i < 64 * 128; i += 256) ws[i] = ldf(W2, i, isbf);
    __syncthreads();

    const int j    = threadIdx.x & 31;
    const int node = (blockIdx.x * 256 + threadIdx.x) >> 5;
    if (node >= n) return;

    unsigned tv = T[(size_t)node * 32 + j];
    const float t0 = lo16(tv);  // dim 2j
    const float t1 = hi16(tv);  // dim 2j+1

    float h[4] = {0.f, 0.f, 0.f, 0.f};  // outputs j, j+32, j+64, j+96
#pragma unroll
    for (int mm = 0; mm < 32; ++mm) {
        float s0 = __shfl(t0, mm, 32);
        float s1 = __shfl(t1, mm, 32);
        const float* w0 = ws + (2 * mm) * 128;
        const float* w1 = ws + (2 * mm + 1) * 128;
#pragma unroll
        for (int q = 0; q < 4; ++q) {
            h[q] = fmaf(s0, w0[j + 32 * q], h[q]);
            h[q] = fmaf(s1, w1[j + 32 * q], h[q]);
        }
    }

    const size_t base = (size_t)node * 128;
#pragma unroll
    for (int q = 0; q < 4; ++q) {
        float o = h[q] + ldf(b2, j + 32 * q, isbf);
        if (isbf) ((bf16*)outp)[base + j + 32 * q] = __float2bfloat16(o);
        else      ((float*)outp)[base + j + 32 * q] = o;
    }
}

extern "C" void kernel_launch(void* const* d_in, const int* in_sizes, int n_in,
                              void* d_out, int out_size, void* d_ws, size_t ws_size,
                              hipStream_t stream) {
    const void* x  = d_in[0];
    const void* ei = d_in[1];
    const void* ew = d_in[2];
    const void* W1 = d_in[3];
    const void* b1 = d_in[4];
    const void* W2 = d_in[5];
    const void* b2 = d_in[6];

    const int n = in_sizes[0] / 128;   // 100000
    const int e = in_sizes[2];         // 1600000
    const int nb = (n + 1023) / 1024;

    // ws layout (4B words) — identical footprint to round 5:
    // flags(8) | deg/dinv(n) | cnt(n) | rp(n+1) | cursor(n) | bsum(1024) | bsx(1024)
    // | pad | epack(2e) | G1/T(32n) | G2(32n)
    // aliases: hist = bsum+512, hcur = bsx+512 (scan only touches [0,nb));
    //          order = cursor (dead after fill)
    int*   flags  = (int*)d_ws;
    float* deg    = (float*)d_ws + 8;            // becomes dinv in scan3
    int*   cnt    = (int*)(deg + n);
    int*   rp     = cnt + n;
    int*   cursor = rp + n + 1;
    int*   bsum   = cursor + n;
    int*   bsx    = bsum + 1024;
    int*   hist   = bsum + 512;
    int*   hcur   = bsx + 512;
    int*   order  = cursor;                      // alias, valid post-fill
    size_t w_off  = (size_t)(8 + 4 * (size_t)n + 1 + 2048);
    w_off = (w_off + 3) & ~(size_t)3;            // 16B align
    uint2*    epack = (uint2*)((int*)d_ws + w_off);
    size_t g_off = w_off + 2 * (size_t)e;
    g_off = (g_off + 3) & ~(size_t)3;
    unsigned* G1 = (unsigned*)d_ws + g_off;      // 32n uints (bf16x2), 16B aligned
    unsigned* G2 = G1 + (size_t)n * 32;

    detect<<<1, 256, 0, stream>>>((const unsigned*)W1, (const unsigned*)ei, flags);
    initk<<<(n + 255) / 256, 256, 0, stream>>>(deg, cnt, hist, n);
    degcnt<<<(e + 255) / 256, 256, 0, stream>>>(ei, ew, deg, cnt, flags, e, n);
    scan1<<<nb, 1024, 0, stream>>>(cnt, rp, bsum, n);
    scan2<<<1, 1024, 0, stream>>>(bsum, bsx, nb);
    scan3<<<(n + 255) / 256, 256, 0, stream>>>(rp, cursor, bsx, deg, n, e);
    fill<<<(e + 255) / 256, 256, 0, stream>>>(ei, ew, cursor, epack, flags, e, n);
    histk<<<(n + 255) / 256, 256, 0, stream>>>(cnt, hist, n);
    hscan<<<1, 256, 0, stream>>>(hist, hcur);
    sortk<<<(n + 255) / 256, 256, 0, stream>>>(cnt, hcur, order, n);

    gemm1<<<1024, 256, 0, stream>>>(x, W1, deg, flags, G1, n);
    agg1<<<(n * 8 + 255) / 256, 256, 0, stream>>>(rp, epack, order, (const uint4*)G1,
                                                  deg, b1, flags, (uint4*)G2, n);
    agg2<<<(n * 8 + 255) / 256, 256, 0, stream>>>(rp, epack, order, (const uint4*)G2,
                                                  deg, (uint4*)G1, n);
    outgemm<<<(n * 32 + 255) / 256, 256, 0, stream>>>(G1, W2, b2, flags, d_out, n);
}

// Round 7
// 1150.134 us; speedup vs baseline: 1.3700x; 1.3700x over previous
//
#include <hip/hip_runtime.h>
#include <hip/hip_bf16.h>

typedef __hip_bfloat16 bf16;
typedef __attribute__((ext_vector_type(8))) short short8;
typedef __attribute__((ext_vector_type(4))) float f32x4;
union V8 { uint4 u; short8 v; };

__device__ __forceinline__ float bf2f(bf16 v) { return __bfloat162float(v); }
__device__ __forceinline__ float lo16(unsigned u) { return __uint_as_float((u & 0xffffu) << 16); }
__device__ __forceinline__ float hi16(unsigned u) { return __uint_as_float(u & 0xffff0000u); }
__device__ __forceinline__ unsigned short f2bfbits(float f) {
    return (unsigned short)(__hip_bfloat16_raw(__float2bfloat16(f)).x);
}
__device__ __forceinline__ unsigned pack2(float a, float b) {
    return (unsigned)f2bfbits(a) | ((unsigned)f2bfbits(b) << 16);
}

// dtype-dispatching loads (flag-driven, uniform branch)
__device__ __forceinline__ float ldf(const void* p, size_t i, bool isbf) {
    return isbf ? bf2f(((const bf16*)p)[i]) : ((const float*)p)[i];
}
__device__ __forceinline__ int ldi(const void* p, size_t i, bool is64) {
    return is64 ? (int)((const long long*)p)[i] : ((const int*)p)[i];
}
__device__ __forceinline__ float sane(float v) {
    return (v == v && fabsf(v) < 1e30f) ? v : 0.f;
}

// ---------------- dtype detection ----------------
__global__ void detect(const unsigned* __restrict__ w1w, const unsigned* __restrict__ eiw,
                       int* __restrict__ flags) {
    __shared__ int cnt[2];
    if (threadIdx.x < 2) cnt[threadIdx.x] = 0;
    __syncthreads();
    int c0 = 0;
    for (int i = threadIdx.x; i < 4096; i += 256) {
        unsigned u = w1w[i];
        unsigned e0 = (u >> 7) & 0xFFu, e1 = (u >> 23) & 0xFFu;
        if (e0 <= 125u && e1 <= 125u) c0++;
    }
    int c1 = 0;
    for (int i = threadIdx.x; i < 2048; i += 256)
        if (eiw[2 * i + 1] == 0u) c1++;
    atomicAdd(&cnt[0], c0);
    atomicAdd(&cnt[1], c1);
    __syncthreads();
    if (threadIdx.x == 0) {
        flags[0] = (cnt[0] >= 3072) ? 1 : 0;
        flags[1] = (cnt[1] >= 1024) ? 1 : 0;
    }
}

// ---------------- init: deg=1, cnt=0, hist=0 ----------------
__global__ void initk(float* __restrict__ deg, int* __restrict__ cnt,
                      int* __restrict__ hist, int n) {
    int i = blockIdx.x * blockDim.x + threadIdx.x;
    if (i < n) { deg[i] = 1.0f; cnt[i] = 0; }
    if (i < 256) hist[i] = 0;
}

// ---------------- count in-degree + weighted degree ----------------
__global__ void degcnt(const void* __restrict__ ei, const void* __restrict__ w,
                       float* __restrict__ deg, int* __restrict__ cnt,
                       const int* __restrict__ flags, int e, int n) {
    const bool isbf = flags[0] != 0;
    const bool is64 = flags[1] != 0;
    int i = blockIdx.x * blockDim.x + threadIdx.x;
    if (i < e) {
        int c = ldi(ei, (size_t)e + i, is64);
        if ((unsigned)c < (unsigned)n) {
            atomicAdd(&cnt[c], 1);
            unsafeAtomicAdd(&deg[c], sane(ldf(w, i, isbf)));
        }
    }
}

// ---------------- scans ----------------
__global__ __launch_bounds__(1024) void scan1(const int* __restrict__ cnt,
                                              int* __restrict__ rp,
                                              int* __restrict__ bsum, int n) {
    __shared__ int s[1024];
    int gid = blockIdx.x * 1024 + threadIdx.x;
    int v = (gid < n) ? cnt[gid] : 0;
    s[threadIdx.x] = v;
    __syncthreads();
    for (int off = 1; off < 1024; off <<= 1) {
        int t = 0;
        if (threadIdx.x >= off) t = s[threadIdx.x - off];
        __syncthreads();
        if (threadIdx.x >= off) s[threadIdx.x] += t;
        __syncthreads();
    }
    if (gid < n) rp[gid] = s[threadIdx.x] - v;
    if (threadIdx.x == 1023) bsum[blockIdx.x] = s[1023];
}

__global__ __launch_bounds__(1024) void scan2(const int* __restrict__ bsum,
                                              int* __restrict__ bsx, int nb) {
    __shared__ int s[1024];
    int v = (threadIdx.x < nb) ? bsum[threadIdx.x] : 0;
    s[threadIdx.x] = v;
    __syncthreads();
    for (int off = 1; off < 1024; off <<= 1) {
        int t = 0;
        if (threadIdx.x >= off) t = s[threadIdx.x - off];
        __syncthreads();
        if (threadIdx.x >= off) s[threadIdx.x] += t;
        __syncthreads();
    }
    if (threadIdx.x < nb) bsx[threadIdx.x] = s[threadIdx.x] - v;
}

// scan3 + degree histogram fused (cnt is final here)
__global__ void scan3(int* __restrict__ rp, int* __restrict__ cursor,
                      const int* __restrict__ bsx, float* __restrict__ deg,
                      const int* __restrict__ cnt, int* __restrict__ hist,
                      int n, int e) {
    int i = blockIdx.x * blockDim.x + threadIdx.x;
    if (i < n) {
        int v = rp[i] + bsx[i >> 10];
        rp[i] = v;
        cursor[i] = v;
        float d = deg[i];
        deg[i] = d > 0.f ? rsqrtf(d) : 0.f;
        atomicAdd(&hist[min(cnt[i], 255)], 1);
    }
    if (i == 0) rp[n] = e;
}

// ---------------- fill CSR ----------------
__global__ void fill(const void* __restrict__ ei, const void* __restrict__ w,
                     int* __restrict__ cursor, uint2* __restrict__ epack,
                     const int* __restrict__ flags, int e, int n) {
    const bool isbf = flags[0] != 0;
    const bool is64 = flags[1] != 0;
    int i = blockIdx.x * blockDim.x + threadIdx.x;
    if (i < e) {
        int r = ldi(ei, (size_t)i, is64);
        int c = ldi(ei, (size_t)e + i, is64);
        if ((unsigned)r < (unsigned)n && (unsigned)c < (unsigned)n) {
            float wv = sane(ldf(w, i, isbf));
            int pos = atomicAdd(&cursor[c], 1);
            epack[pos] = make_uint2((unsigned)r, __float_as_uint(wv));
        }
    }
}

// ---------------- degree-bucket scan + counting sort ----------------
__global__ void hscan(const int* __restrict__ hist, int* __restrict__ hcur) {
    __shared__ int s[256];
    int v = hist[threadIdx.x];
    s[threadIdx.x] = v;
    __syncthreads();
    for (int off = 1; off < 256; off <<= 1) {
        int t = 0;
        if (threadIdx.x >= off) t = s[threadIdx.x - off];
        __syncthreads();
        if (threadIdx.x >= off) s[threadIdx.x] += t;
        __syncthreads();
    }
    hcur[threadIdx.x] = s[threadIdx.x] - v;  // exclusive
}

__global__ void sortk(const int* __restrict__ cnt, int* __restrict__ hcur,
                      int* __restrict__ order, int n) {
    int i = blockIdx.x * blockDim.x + threadIdx.x;
    if (i < n) {
        int pos = atomicAdd(&hcur[min(cnt[i], 255)], 1);
        order[pos] = i;
    }
}

// ---- layer1 GEMM via MFMA: G1 = bf16(dinv ⊙ (X[n,128] @ W1[128,64])) ----
// One wave per 16-row chunk. B pre-packed in LDS in fragment-lane order.
__global__ __launch_bounds__(256) void gemm1_mfma(const void* __restrict__ x,
                                                  const void* __restrict__ W1,
                                                  const float* __restrict__ dinv,
                                                  const int* __restrict__ flags,
                                                  unsigned short* __restrict__ G1,
                                                  int n) {
    const bool isbf = flags[0] != 0;
    __shared__ uint4 bfr[16 * 64];  // [ct*4+ks][lane], 16 KB
    for (int idx = threadIdx.x; idx < 16 * 64; idx += 256) {
        int lane = idx & 63, fr = idx >> 6;
        int ct = fr >> 2, ks = fr & 3;
        int k0 = ks * 32 + (lane >> 4) * 8;
        int col = ct * 16 + (lane & 15);
        unsigned short h[8];
#pragma unroll
        for (int j = 0; j < 8; ++j)
            h[j] = f2bfbits(ldf(W1, (size_t)(k0 + j) * 64 + col, isbf));
        bfr[idx] = make_uint4((unsigned)h[0] | ((unsigned)h[1] << 16),
                              (unsigned)h[2] | ((unsigned)h[3] << 16),
                              (unsigned)h[4] | ((unsigned)h[5] << 16),
                              (unsigned)h[6] | ((unsigned)h[7] << 16));
    }
    __syncthreads();

    const int lane = threadIdx.x & 63;
    const int m = lane & 15, q = lane >> 4;
    const int wid = (blockIdx.x * 256 + threadIdx.x) >> 6;
    const int nw  = (gridDim.x * 256) >> 6;
    const int nchunk = (n + 15) >> 4;

    for (int ch = wid; ch < nchunk; ch += nw) {
        const int row0 = ch * 16;
        const int rA = min(row0 + m, n - 1);
        V8 a[4];
        if (isbf) {
            const uint4* xr = (const uint4*)((const bf16*)x + (size_t)rA * 128);
#pragma unroll
            for (int ks = 0; ks < 4; ++ks) a[ks].u = xr[ks * 4 + q];
        } else {
            const float* xr = (const float*)x + (size_t)rA * 128;
#pragma unroll
            for (int ks = 0; ks < 4; ++ks) {
                unsigned short h[8];
#pragma unroll
                for (int j = 0; j < 8; ++j) h[j] = f2bfbits(xr[ks * 32 + q * 8 + j]);
                a[ks].u = make_uint4((unsigned)h[0] | ((unsigned)h[1] << 16),
                                     (unsigned)h[2] | ((unsigned)h[3] << 16),
                                     (unsigned)h[4] | ((unsigned)h[5] << 16),
                                     (unsigned)h[6] | ((unsigned)h[7] << 16));
            }
        }
#pragma unroll
        for (int ct = 0; ct < 4; ++ct) {
            f32x4 acc = {0.f, 0.f, 0.f, 0.f};
#pragma unroll
            for (int ks = 0; ks < 4; ++ks) {
                V8 b; b.u = bfr[(ct * 4 + ks) * 64 + lane];
                acc = __builtin_amdgcn_mfma_f32_16x16x32_bf16(a[ks].v, b.v, acc, 0, 0, 0);
            }
#pragma unroll
            for (int r = 0; r < 4; ++r) {
                int row = row0 + q * 4 + r;
                if (row < n)
                    G1[(size_t)row * 64 + ct * 16 + m] = f2bfbits(dinv[row] * acc[r]);
            }
        }
    }
}

// ---- gather core: 8 lanes/node, uint4/lane, depth-8 + epack prefetch ----
__device__ __forceinline__ void gacc8(const int* __restrict__ rp,
                                      const uint2* __restrict__ epack,
                                      const uint4* __restrict__ Gv,
                                      int node, int sub, float acc[8]) {
    uint4 self = Gv[(size_t)node * 8 + sub];
    acc[0] = lo16(self.x); acc[1] = hi16(self.x);
    acc[2] = lo16(self.y); acc[3] = hi16(self.y);
    acc[4] = lo16(self.z); acc[5] = hi16(self.z);
    acc[6] = lo16(self.w); acc[7] = hi16(self.w);

    const int s0 = rp[node], s1 = rp[node + 1];
    const uint2 fb = make_uint2((unsigned)node, 0u);
    int idx = s0 + sub;
    uint2 ld = (idx < s1) ? epack[idx] : fb;
    for (int base = s0; base < s1; base += 8) {
        int nidx = base + 8 + sub;
        uint2 nld = (nidx < s1) ? epack[nidx] : fb;  // prefetch next batch
        int rr[8]; float wv[8];
#pragma unroll
        for (int u = 0; u < 8; ++u) {
            rr[u] = __shfl((int)ld.x, u, 8);
            wv[u] = __uint_as_float((unsigned)__shfl((int)ld.y, u, 8));
        }
        uint4 gp[8];
#pragma unroll
        for (int u = 0; u < 8; ++u) gp[u] = Gv[(size_t)rr[u] * 8 + sub];
#pragma unroll
        for (int u = 0; u < 8; ++u) {
            acc[0] = fmaf(wv[u], lo16(gp[u].x), acc[0]);
            acc[1] = fmaf(wv[u], hi16(gp[u].x), acc[1]);
            acc[2] = fmaf(wv[u], lo16(gp[u].y), acc[2]);
            acc[3] = fmaf(wv[u], hi16(gp[u].y), acc[3]);
            acc[4] = fmaf(wv[u], lo16(gp[u].z), acc[4]);
            acc[5] = fmaf(wv[u], hi16(gp[u].z), acc[5]);
            acc[6] = fmaf(wv[u], lo16(gp[u].w), acc[6]);
            acc[7] = fmaf(wv[u], hi16(gp[u].w), acc[7]);
        }
        ld = nld;
    }
}

// ---- agg1: acc -> relu/bias/dinv -> G2 ----
__global__ __launch_bounds__(256, 4) void agg1(const int* __restrict__ rp,
                                               const uint2* __restrict__ epack,
                                               const int* __restrict__ order,
                                               const uint4* __restrict__ G1v,
                                               const float* __restrict__ dinv,
                                               const void* __restrict__ b1,
                                               const int* __restrict__ flags,
                                               uint4* __restrict__ G2v, int n) {
    const bool isbf = flags[0] != 0;
    const int sub = threadIdx.x & 7;
    const int g   = (blockIdx.x * 256 + threadIdx.x) >> 3;
    if (g >= n) return;
    const int node = order[g];

    float acc[8];
    gacc8(rp, epack, G1v, node, sub, acc);

    const float dv = dinv[node];
    unsigned o[4];
#pragma unroll
    for (int t = 0; t < 4; ++t) {
        float h0 = dv * acc[2 * t]     + ldf(b1, 8 * sub + 2 * t, isbf);
        float h1 = dv * acc[2 * t + 1] + ldf(b1, 8 * sub + 2 * t + 1, isbf);
        h0 = h0 > 0.f ? h0 : 0.f;
        h1 = h1 > 0.f ? h1 : 0.f;
        o[t] = pack2(dv * h0, dv * h1);
    }
    G2v[(size_t)node * 8 + sub] = make_uint4(o[0], o[1], o[2], o[3]);
}

// ---- agg2: acc -> T = bf16(dinv * acc) ----
__global__ __launch_bounds__(256, 4) void agg2(const int* __restrict__ rp,
                                               const uint2* __restrict__ epack,
                                               const int* __restrict__ order,
                                               const uint4* __restrict__ G2v,
                                               const float* __restrict__ dinv,
                                               uint4* __restrict__ Tv, int n) {
    const int sub = threadIdx.x & 7;
    const int g   = (blockIdx.x * 256 + threadIdx.x) >> 3;
    if (g >= n) return;
    const int node = order[g];

    float acc[8];
    gacc8(rp, epack, G2v, node, sub, acc);

    const float dv = dinv[node];
    uint4 o;
    o.x = pack2(dv * acc[0], dv * acc[1]);
    o.y = pack2(dv * acc[2], dv * acc[3]);
    o.z = pack2(dv * acc[4], dv * acc[5]);
    o.w = pack2(dv * acc[6], dv * acc[7]);
    Tv[(size_t)node * 8 + sub] = o;
}

// ---- outgemm via MFMA: out = T[n,64] @ W2[64,128] + b2 ----
__global__ __launch_bounds__(256) void outgemm_mfma(const bf16* __restrict__ T,
                                                    const void* __restrict__ W2,
                                                    const void* __restrict__ b2,
                                                    const int* __restrict__ flags,
                                                    void* __restrict__ outp, int n) {
    const bool isbf = flags[0] != 0;
    __shared__ uint4 bfr[16 * 64];   // [ct*2+ks][lane], 16 KB
    __shared__ float b2s[128];
    for (int idx = threadIdx.x; idx < 16 * 64; idx += 256) {
        int lane = idx & 63, fr = idx >> 6;
        int ct = fr >> 1, ks = fr & 1;
        int k0 = ks * 32 + (lane >> 4) * 8;
        int col = ct * 16 + (lane & 15);
        unsigned short h[8];
#pragma unroll
        for (int j = 0; j < 8; ++j)
            h[j] = f2bfbits(ldf(W2, (size_t)(k0 + j) * 128 + col, isbf));
        bfr[idx] = make_uint4((unsigned)h[0] | ((unsigned)h[1] << 16),
                              (unsigned)h[2] | ((unsigned)h[3] << 16),
                              (unsigned)h[4] | ((unsigned)h[5] << 16),
                              (unsigned)h[6] | ((unsigned)h[7] << 16));
    }
    for (int i = threadIdx.x; i < 128; i += 256) b2s[i] = ldf(b2, i, isbf);
    __syncthreads();

    const int lane = threadIdx.x & 63;
    const int m = lane & 15, q = lane >> 4;
    const int wid = (blockIdx.x * 256 + threadIdx.x) >> 6;
    const int nw  = (gridDim.x * 256) >> 6;
    const int nchunk = (n + 15) >> 4;

    for (int ch = wid; ch < nchunk; ch += nw) {
        const int row0 = ch * 16;
        const int rA = min(row0 + m, n - 1);
        const uint4* tr = (const uint4*)(T + (size_t)rA * 64);
        V8 a[2];
        a[0].u = tr[q];        // k = 0*32 + q*8 + j
        a[1].u = tr[4 + q];    // k = 32 + q*8 + j
#pragma unroll
        for (int ct = 0; ct < 8; ++ct) {
            f32x4 acc = {0.f, 0.f, 0.f, 0.f};
#pragma unroll
            for (int ks = 0; ks < 2; ++ks) {
                V8 b; b.u = bfr[(ct * 2 + ks) * 64 + lane];
                acc = __builtin_amdgcn_mfma_f32_16x16x32_bf16(a[ks].v, b.v, acc, 0, 0, 0);
            }
            const int col = ct * 16 + m;
            const float bb = b2s[col];
#pragma unroll
            for (int r = 0; r < 4; ++r) {
                int row = row0 + q * 4 + r;
                if (row < n) {
                    float o = acc[r] + bb;
                    if (isbf) ((bf16*)outp)[(size_t)row * 128 + col] = __float2bfloat16(o);
                    else      ((float*)outp)[(size_t)row * 128 + col] = o;
                }
            }
        }
    }
}

extern "C" void kernel_launch(void* const* d_in, const int* in_sizes, int n_in,
                              void* d_out, int out_size, void* d_ws, size_t ws_size,
                              hipStream_t stream) {
    const void* x  = d_in[0];
    const void* ei = d_in[1];
    const void* ew = d_in[2];
    const void* W1 = d_in[3];
    const void* b1 = d_in[4];
    const void* W2 = d_in[5];
    const void* b2 = d_in[6];

    const int n = in_sizes[0] / 128;   // 100000
    const int e = in_sizes[2];         // 1600000
    const int nb = (n + 1023) / 1024;

    // ws layout (4B words):
    // flags(8) | deg/dinv(n) | cnt(n) | rp(n+1) | cursor(n) | bsum(1024) | bsx(1024)
    // | pad | epack(2e) | G1/T(32n) | G2(32n)
    // aliases: hist = bsum+512, hcur = bsx+512; order = cursor (dead after fill)
    int*   flags  = (int*)d_ws;
    float* deg    = (float*)d_ws + 8;            // becomes dinv in scan3
    int*   cnt    = (int*)(deg + n);
    int*   rp     = cnt + n;
    int*   cursor = rp + n + 1;
    int*   bsum   = cursor + n;
    int*   bsx    = bsum + 1024;
    int*   hist   = bsum + 512;
    int*   hcur   = bsx + 512;
    int*   order  = cursor;                      // alias, valid post-fill
    size_t w_off  = (size_t)(8 + 4 * (size_t)n + 1 + 2048);
    w_off = (w_off + 3) & ~(size_t)3;            // 16B align
    uint2*    epack = (uint2*)((int*)d_ws + w_off);
    size_t g_off = w_off + 2 * (size_t)e;
    g_off = (g_off + 3) & ~(size_t)3;
    unsigned* G1 = (unsigned*)d_ws + g_off;      // 32n uints (bf16x2), 16B aligned
    unsigned* G2 = G1 + (size_t)n * 32;

    detect<<<1, 256, 0, stream>>>((const unsigned*)W1, (const unsigned*)ei, flags);
    initk<<<(n + 255) / 256, 256, 0, stream>>>(deg, cnt, hist, n);
    degcnt<<<(e + 255) / 256, 256, 0, stream>>>(ei, ew, deg, cnt, flags, e, n);
    scan1<<<nb, 1024, 0, stream>>>(cnt, rp, bsum, n);
    scan2<<<1, 1024, 0, stream>>>(bsum, bsx, nb);
    scan3<<<(n + 255) / 256, 256, 0, stream>>>(rp, cursor, bsx, deg, cnt, hist, n, e);
    fill<<<(e + 255) / 256, 256, 0, stream>>>(ei, ew, cursor, epack, flags, e, n);
    hscan<<<1, 256, 0, stream>>>(hist, hcur);
    sortk<<<(n + 255) / 256, 256, 0, stream>>>(cnt, hcur, order, n);

    gemm1_mfma<<<192, 256, 0, stream>>>(x, W1, deg, flags, (unsigned short*)G1, n);
    agg1<<<(n * 8 + 255) / 256, 256, 0, stream>>>(rp, epack, order, (const uint4*)G1,
                                                  deg, b1, flags, (uint4*)G2, n);
    agg2<<<(n * 8 + 255) / 256, 256, 0, stream>>>(rp, epack, order, (const uint4*)G2,
                                                  deg, (uint4*)G1, n);
    outgemm_mfma<<<192, 256, 0, stream>>>((const bf16*)G1, W2, b2, flags, d_out, n);
}

// Round 8
// 875.006 us; speedup vs baseline: 1.8007x; 1.3144x over previous
//
#include <hip/hip_runtime.h>
#include <hip/hip_bf16.h>

typedef __hip_bfloat16 bf16;
typedef __attribute__((ext_vector_type(8))) short short8;
typedef __attribute__((ext_vector_type(4))) float f32x4;
union V8 { uint4 u; short8 v; };

__device__ __forceinline__ float bf2f(bf16 v) { return __bfloat162float(v); }
__device__ __forceinline__ float lo16(unsigned u) { return __uint_as_float((u & 0xffffu) << 16); }
__device__ __forceinline__ float hi16(unsigned u) { return __uint_as_float(u & 0xffff0000u); }
__device__ __forceinline__ unsigned short f2bfbits(float f) {
    return (unsigned short)(__hip_bfloat16_raw(__float2bfloat16(f)).x);
}
__device__ __forceinline__ unsigned pack2(float a, float b) {
    return (unsigned)f2bfbits(a) | ((unsigned)f2bfbits(b) << 16);
}

// dtype-dispatching loads (flag-driven, uniform branch)
__device__ __forceinline__ float ldf(const void* p, size_t i, bool isbf) {
    return isbf ? bf2f(((const bf16*)p)[i]) : ((const float*)p)[i];
}
__device__ __forceinline__ int ldi(const void* p, size_t i, bool is64) {
    return is64 ? (int)((const long long*)p)[i] : ((const int*)p)[i];
}
__device__ __forceinline__ float sane(float v) {
    return (v == v && fabsf(v) < 1e30f) ? v : 0.f;
}

// ---------------- dtype detection ----------------
__global__ void detect(const unsigned* __restrict__ w1w, const unsigned* __restrict__ eiw,
                       int* __restrict__ flags) {
    __shared__ int cnt[2];
    if (threadIdx.x < 2) cnt[threadIdx.x] = 0;
    __syncthreads();
    int c0 = 0;
    for (int i = threadIdx.x; i < 4096; i += 256) {
        unsigned u = w1w[i];
        unsigned e0 = (u >> 7) & 0xFFu, e1 = (u >> 23) & 0xFFu;
        if (e0 <= 125u && e1 <= 125u) c0++;
    }
    int c1 = 0;
    for (int i = threadIdx.x; i < 2048; i += 256)
        if (eiw[2 * i + 1] == 0u) c1++;
    atomicAdd(&cnt[0], c0);
    atomicAdd(&cnt[1], c1);
    __syncthreads();
    if (threadIdx.x == 0) {
        flags[0] = (cnt[0] >= 3072) ? 1 : 0;
        flags[1] = (cnt[1] >= 1024) ? 1 : 0;
    }
}

// ---------------- init: deg=1, cnt=0, hist=0 ----------------
__global__ void initk(float* __restrict__ deg, int* __restrict__ cnt,
                      int* __restrict__ hist, int n) {
    int i = blockIdx.x * blockDim.x + threadIdx.x;
    if (i < n) { deg[i] = 1.0f; cnt[i] = 0; }
    if (i < 256) hist[i] = 0;
}

// ---------------- count in-degree + weighted degree ----------------
__global__ void degcnt(const void* __restrict__ ei, const void* __restrict__ w,
                       float* __restrict__ deg, int* __restrict__ cnt,
                       const int* __restrict__ flags, int e, int n) {
    const bool isbf = flags[0] != 0;
    const bool is64 = flags[1] != 0;
    int i = blockIdx.x * blockDim.x + threadIdx.x;
    if (i < e) {
        int c = ldi(ei, (size_t)e + i, is64);
        if ((unsigned)c < (unsigned)n) {
            atomicAdd(&cnt[c], 1);
            unsafeAtomicAdd(&deg[c], sane(ldf(w, i, isbf)));
        }
    }
}

// ---------------- scans ----------------
__global__ __launch_bounds__(1024) void scan1(const int* __restrict__ cnt,
                                              int* __restrict__ rp,
                                              int* __restrict__ bsum, int n) {
    __shared__ int s[1024];
    int gid = blockIdx.x * 1024 + threadIdx.x;
    int v = (gid < n) ? cnt[gid] : 0;
    s[threadIdx.x] = v;
    __syncthreads();
    for (int off = 1; off < 1024; off <<= 1) {
        int t = 0;
        if (threadIdx.x >= off) t = s[threadIdx.x - off];
        __syncthreads();
        if (threadIdx.x >= off) s[threadIdx.x] += t;
        __syncthreads();
    }
    if (gid < n) rp[gid] = s[threadIdx.x] - v;
    if (threadIdx.x == 1023) bsum[blockIdx.x] = s[1023];
}

__global__ __launch_bounds__(1024) void scan2(const int* __restrict__ bsum,
                                              int* __restrict__ bsx, int nb) {
    __shared__ int s[1024];
    int v = (threadIdx.x < nb) ? bsum[threadIdx.x] : 0;
    s[threadIdx.x] = v;
    __syncthreads();
    for (int off = 1; off < 1024; off <<= 1) {
        int t = 0;
        if (threadIdx.x >= off) t = s[threadIdx.x - off];
        __syncthreads();
        if (threadIdx.x >= off) s[threadIdx.x] += t;
        __syncthreads();
    }
    if (threadIdx.x < nb) bsx[threadIdx.x] = s[threadIdx.x] - v;
}

// scan3 + degree histogram fused (cnt is final here)
__global__ void scan3(int* __restrict__ rp, int* __restrict__ cursor,
                      const int* __restrict__ bsx, float* __restrict__ deg,
                      const int* __restrict__ cnt, int* __restrict__ hist,
                      int n, int e) {
    int i = blockIdx.x * blockDim.x + threadIdx.x;
    if (i < n) {
        int v = rp[i] + bsx[i >> 10];
        rp[i] = v;
        cursor[i] = v;
        float d = deg[i];
        deg[i] = d > 0.f ? rsqrtf(d) : 0.f;
        atomicAdd(&hist[min(cnt[i], 255)], 1);
    }
    if (i == 0) rp[n] = e;
}

// ---------------- fill CSR ----------------
__global__ void fill(const void* __restrict__ ei, const void* __restrict__ w,
                     int* __restrict__ cursor, uint2* __restrict__ epack,
                     const int* __restrict__ flags, int e, int n) {
    const bool isbf = flags[0] != 0;
    const bool is64 = flags[1] != 0;
    int i = blockIdx.x * blockDim.x + threadIdx.x;
    if (i < e) {
        int r = ldi(ei, (size_t)i, is64);
        int c = ldi(ei, (size_t)e + i, is64);
        if ((unsigned)r < (unsigned)n && (unsigned)c < (unsigned)n) {
            float wv = sane(ldf(w, i, isbf));
            int pos = atomicAdd(&cursor[c], 1);
            epack[pos] = make_uint2((unsigned)r, __float_as_uint(wv));
        }
    }
}

// ---------------- degree-bucket scan ----------------
__global__ void hscan(const int* __restrict__ hist, int* __restrict__ hcur) {
    __shared__ int s[256];
    int v = hist[threadIdx.x];
    s[threadIdx.x] = v;
    __syncthreads();
    for (int off = 1; off < 256; off <<= 1) {
        int t = 0;
        if (threadIdx.x >= off) t = s[threadIdx.x - off];
        __syncthreads();
        if (threadIdx.x >= off) s[threadIdx.x] += t;
        __syncthreads();
    }
    hcur[threadIdx.x] = s[threadIdx.x] - v;  // exclusive
}

// ---------------- counting-sort placement, block-aggregated ----------------
// LDS histogram + intra-block ranks; ONE global fetch-add per (block, bin)
// reserves a whole range -> ~4k uncontended atomics instead of 100k contended.
__global__ __launch_bounds__(1024) void sortk(const int* __restrict__ cnt,
                                              int* __restrict__ hcur,
                                              int* __restrict__ order, int n) {
    __shared__ int lh[256];     // local histogram (then reused as-is)
    __shared__ int lbase[256];  // global base per bin for this block
    const int t = threadIdx.x;
    for (int b = t; b < 256; b += 1024) lh[b] = 0;
    __syncthreads();
    const int i = blockIdx.x * 1024 + t;
    int b = 0, lrank = 0;
    if (i < n) {
        b = min(cnt[i], 255);
        lrank = atomicAdd(&lh[b], 1);  // LDS atomic: intra-block rank
    }
    __syncthreads();
    for (int bb = t; bb < 256; bb += 1024) {
        int c = lh[bb];
        lbase[bb] = (c > 0) ? atomicAdd(&hcur[bb], c) : 0;  // range reservation
    }
    __syncthreads();
    if (i < n) order[lbase[b] + lrank] = i;
}

// ---- layer1 GEMM via MFMA: G1 = bf16(dinv ⊙ (X[n,128] @ W1[128,64])) ----
__global__ __launch_bounds__(256) void gemm1_mfma(const void* __restrict__ x,
                                                  const void* __restrict__ W1,
                                                  const float* __restrict__ dinv,
                                                  const int* __restrict__ flags,
                                                  unsigned short* __restrict__ G1,
                                                  int n) {
    const bool isbf = flags[0] != 0;
    __shared__ uint4 bfr[16 * 64];  // [ct*4+ks][lane], 16 KB
    for (int idx = threadIdx.x; idx < 16 * 64; idx += 256) {
        int lane = idx & 63, fr = idx >> 6;
        int ct = fr >> 2, ks = fr & 3;
        int k0 = ks * 32 + (lane >> 4) * 8;
        int col = ct * 16 + (lane & 15);
        unsigned short h[8];
#pragma unroll
        for (int j = 0; j < 8; ++j)
            h[j] = f2bfbits(ldf(W1, (size_t)(k0 + j) * 64 + col, isbf));
        bfr[idx] = make_uint4((unsigned)h[0] | ((unsigned)h[1] << 16),
                              (unsigned)h[2] | ((unsigned)h[3] << 16),
                              (unsigned)h[4] | ((unsigned)h[5] << 16),
                              (unsigned)h[6] | ((unsigned)h[7] << 16));
    }
    __syncthreads();

    const int lane = threadIdx.x & 63;
    const int m = lane & 15, q = lane >> 4;
    const int wid = (blockIdx.x * 256 + threadIdx.x) >> 6;
    const int nw  = (gridDim.x * 256) >> 6;
    const int nchunk = (n + 15) >> 4;

    for (int ch = wid; ch < nchunk; ch += nw) {
        const int row0 = ch * 16;
        const int rA = min(row0 + m, n - 1);
        V8 a[4];
        if (isbf) {
            const uint4* xr = (const uint4*)((const bf16*)x + (size_t)rA * 128);
#pragma unroll
            for (int ks = 0; ks < 4; ++ks) a[ks].u = xr[ks * 4 + q];
        } else {
            const float* xr = (const float*)x + (size_t)rA * 128;
#pragma unroll
            for (int ks = 0; ks < 4; ++ks) {
                unsigned short h[8];
#pragma unroll
                for (int j = 0; j < 8; ++j) h[j] = f2bfbits(xr[ks * 32 + q * 8 + j]);
                a[ks].u = make_uint4((unsigned)h[0] | ((unsigned)h[1] << 16),
                                     (unsigned)h[2] | ((unsigned)h[3] << 16),
                                     (unsigned)h[4] | ((unsigned)h[5] << 16),
                                     (unsigned)h[6] | ((unsigned)h[7] << 16));
            }
        }
#pragma unroll
        for (int ct = 0; ct < 4; ++ct) {
            f32x4 acc = {0.f, 0.f, 0.f, 0.f};
#pragma unroll
            for (int ks = 0; ks < 4; ++ks) {
                V8 b; b.u = bfr[(ct * 4 + ks) * 64 + lane];
                acc = __builtin_amdgcn_mfma_f32_16x16x32_bf16(a[ks].v, b.v, acc, 0, 0, 0);
            }
#pragma unroll
            for (int r = 0; r < 4; ++r) {
                int row = row0 + q * 4 + r;
                if (row < n)
                    G1[(size_t)row * 64 + ct * 16 + m] = f2bfbits(dinv[row] * acc[r]);
            }
        }
    }
}

// ---- gather core: 8 lanes/node, uint4/lane, depth-8 + epack prefetch ----
__device__ __forceinline__ void gacc8(const int* __restrict__ rp,
                                      const uint2* __restrict__ epack,
                                      const uint4* __restrict__ Gv,
                                      int node, int sub, float acc[8]) {
    uint4 self = Gv[(size_t)node * 8 + sub];
    acc[0] = lo16(self.x); acc[1] = hi16(self.x);
    acc[2] = lo16(self.y); acc[3] = hi16(self.y);
    acc[4] = lo16(self.z); acc[5] = hi16(self.z);
    acc[6] = lo16(self.w); acc[7] = hi16(self.w);

    const int s0 = rp[node], s1 = rp[node + 1];
    const uint2 fb = make_uint2((unsigned)node, 0u);
    int idx = s0 + sub;
    uint2 ld = (idx < s1) ? epack[idx] : fb;
    for (int base = s0; base < s1; base += 8) {
        int nidx = base + 8 + sub;
        uint2 nld = (nidx < s1) ? epack[nidx] : fb;  // prefetch next batch
        int rr[8]; float wv[8];
#pragma unroll
        for (int u = 0; u < 8; ++u) {
            rr[u] = __shfl((int)ld.x, u, 8);
            wv[u] = __uint_as_float((unsigned)__shfl((int)ld.y, u, 8));
        }
        uint4 gp[8];
#pragma unroll
        for (int u = 0; u < 8; ++u) gp[u] = Gv[(size_t)rr[u] * 8 + sub];
#pragma unroll
        for (int u = 0; u < 8; ++u) {
            acc[0] = fmaf(wv[u], lo16(gp[u].x), acc[0]);
            acc[1] = fmaf(wv[u], hi16(gp[u].x), acc[1]);
            acc[2] = fmaf(wv[u], lo16(gp[u].y), acc[2]);
            acc[3] = fmaf(wv[u], hi16(gp[u].y), acc[3]);
            acc[4] = fmaf(wv[u], lo16(gp[u].z), acc[4]);
            acc[5] = fmaf(wv[u], hi16(gp[u].z), acc[5]);
            acc[6] = fmaf(wv[u], lo16(gp[u].w), acc[6]);
            acc[7] = fmaf(wv[u], hi16(gp[u].w), acc[7]);
        }
        ld = nld;
    }
}

// ---- agg1: acc -> relu/bias/dinv -> G2 ----
__global__ __launch_bounds__(256, 4) void agg1(const int* __restrict__ rp,
                                               const uint2* __restrict__ epack,
                                               const int* __restrict__ order,
                                               const uint4* __restrict__ G1v,
                                               const float* __restrict__ dinv,
                                               const void* __restrict__ b1,
                                               const int* __restrict__ flags,
                                               uint4* __restrict__ G2v, int n) {
    const bool isbf = flags[0] != 0;
    const int sub = threadIdx.x & 7;
    const int g   = (blockIdx.x * 256 + threadIdx.x) >> 3;
    if (g >= n) return;
    const int node = order[g];

    float acc[8];
    gacc8(rp, epack, G1v, node, sub, acc);

    const float dv = dinv[node];
    unsigned o[4];
#pragma unroll
    for (int t = 0; t < 4; ++t) {
        float h0 = dv * acc[2 * t]     + ldf(b1, 8 * sub + 2 * t, isbf);
        float h1 = dv * acc[2 * t + 1] + ldf(b1, 8 * sub + 2 * t + 1, isbf);
        h0 = h0 > 0.f ? h0 : 0.f;
        h1 = h1 > 0.f ? h1 : 0.f;
        o[t] = pack2(dv * h0, dv * h1);
    }
    G2v[(size_t)node * 8 + sub] = make_uint4(o[0], o[1], o[2], o[3]);
}

// ---- agg2: acc -> T = bf16(dinv * acc) ----
__global__ __launch_bounds__(256, 4) void agg2(const int* __restrict__ rp,
                                               const uint2* __restrict__ epack,
                                               const int* __restrict__ order,
                                               const uint4* __restrict__ G2v,
                                               const float* __restrict__ dinv,
                                               uint4* __restrict__ Tv, int n) {
    const int sub = threadIdx.x & 7;
    const int g   = (blockIdx.x * 256 + threadIdx.x) >> 3;
    if (g >= n) return;
    const int node = order[g];

    float acc[8];
    gacc8(rp, epack, G2v, node, sub, acc);

    const float dv = dinv[node];
    uint4 o;
    o.x = pack2(dv * acc[0], dv * acc[1]);
    o.y = pack2(dv * acc[2], dv * acc[3]);
    o.z = pack2(dv * acc[4], dv * acc[5]);
    o.w = pack2(dv * acc[6], dv * acc[7]);
    Tv[(size_t)node * 8 + sub] = o;
}

// ---- outgemm via MFMA: out = T[n,64] @ W2[64,128] + b2 ----
__global__ __launch_bounds__(256) void outgemm_mfma(const bf16* __restrict__ T,
                                                    const void* __restrict__ W2,
                                                    const void* __restrict__ b2,
                                                    const int* __restrict__ flags,
                                                    void* __restrict__ outp, int n) {
    const bool isbf = flags[0] != 0;
    __shared__ uint4 bfr[16 * 64];   // [ct*2+ks][lane], 16 KB
    __shared__ float b2s[128];
    for (int idx = threadIdx.x; idx < 16 * 64; idx += 256) {
        int lane = idx & 63, fr = idx >> 6;
        int ct = fr >> 1, ks = fr & 1;
        int k0 = ks * 32 + (lane >> 4) * 8;
        int col = ct * 16 + (lane & 15);
        unsigned short h[8];
#pragma unroll
        for (int j = 0; j < 8; ++j)
            h[j] = f2bfbits(ldf(W2, (size_t)(k0 + j) * 128 + col, isbf));
        bfr[idx] = make_uint4((unsigned)h[0] | ((unsigned)h[1] << 16),
                              (unsigned)h[2] | ((unsigned)h[3] << 16),
                              (unsigned)h[4] | ((unsigned)h[5] << 16),
                              (unsigned)h[6] | ((unsigned)h[7] << 16));
    }
    for (int i = threadIdx.x; i < 128; i += 256) b2s[i] = ldf(b2, i, isbf);
    __syncthreads();

    const int lane = threadIdx.x & 63;
    const int m = lane & 15, q = lane >> 4;
    const int wid = (blockIdx.x * 256 + threadIdx.x) >> 6;
    const int nw  = (gridDim.x * 256) >> 6;
    const int nchunk = (n + 15) >> 4;

    for (int ch = wid; ch < nchunk; ch += nw) {
        const int row0 = ch * 16;
        const int rA = min(row0 + m, n - 1);
        const uint4* tr = (const uint4*)(T + (size_t)rA * 64);
        V8 a[2];
        a[0].u = tr[q];        // k = 0*32 + q*8 + j
        a[1].u = tr[4 + q];    // k = 32 + q*8 + j
#pragma unroll
        for (int ct = 0; ct < 8; ++ct) {
            f32x4 acc = {0.f, 0.f, 0.f, 0.f};
#pragma unroll
            for (int ks = 0; ks < 2; ++ks) {
                V8 b; b.u = bfr[(ct * 2 + ks) * 64 + lane];
                acc = __builtin_amdgcn_mfma_f32_16x16x32_bf16(a[ks].v, b.v, acc, 0, 0, 0);
            }
            const int col = ct * 16 + m;
            const float bb = b2s[col];
#pragma unroll
            for (int r = 0; r < 4; ++r) {
                int row = row0 + q * 4 + r;
                if (row < n) {
                    float o = acc[r] + bb;
                    if (isbf) ((bf16*)outp)[(size_t)row * 128 + col] = __float2bfloat16(o);
                    else      ((float*)outp)[(size_t)row * 128 + col] = o;
                }
            }
        }
    }
}

extern "C" void kernel_launch(void* const* d_in, const int* in_sizes, int n_in,
                              void* d_out, int out_size, void* d_ws, size_t ws_size,
                              hipStream_t stream) {
    const void* x  = d_in[0];
    const void* ei = d_in[1];
    const void* ew = d_in[2];
    const void* W1 = d_in[3];
    const void* b1 = d_in[4];
    const void* W2 = d_in[5];
    const void* b2 = d_in[6];

    const int n = in_sizes[0] / 128;   // 100000
    const int e = in_sizes[2];         // 1600000
    const int nb = (n + 1023) / 1024;

    // ws layout (4B words):
    // flags(8) | deg/dinv(n) | cnt(n) | rp(n+1) | cursor(n) | bsum(1024) | bsx(1024)
    // | pad | epack(2e) | G1/T(32n) | G2(32n)
    // aliases: hist = bsum+512, hcur = bsx+512; order = cursor (dead after fill)
    int*   flags  = (int*)d_ws;
    float* deg    = (float*)d_ws + 8;            // becomes dinv in scan3
    int*   cnt    = (int*)(deg + n);
    int*   rp     = cnt + n;
    int*   cursor = rp + n + 1;
    int*   bsum   = cursor + n;
    int*   bsx    = bsum + 1024;
    int*   hist   = bsum + 512;
    int*   hcur   = bsx + 512;
    int*   order  = cursor;                      // alias, valid post-fill
    size_t w_off  = (size_t)(8 + 4 * (size_t)n + 1 + 2048);
    w_off = (w_off + 3) & ~(size_t)3;            // 16B align
    uint2*    epack = (uint2*)((int*)d_ws + w_off);
    size_t g_off = w_off + 2 * (size_t)e;
    g_off = (g_off + 3) & ~(size_t)3;
    unsigned* G1 = (unsigned*)d_ws + g_off;      // 32n uints (bf16x2), 16B aligned
    unsigned* G2 = G1 + (size_t)n * 32;

    detect<<<1, 256, 0, stream>>>((const unsigned*)W1, (const unsigned*)ei, flags);
    initk<<<(n + 255) / 256, 256, 0, stream>>>(deg, cnt, hist, n);
    degcnt<<<(e + 255) / 256, 256, 0, stream>>>(ei, ew, deg, cnt, flags, e, n);
    scan1<<<nb, 1024, 0, stream>>>(cnt, rp, bsum, n);
    scan2<<<1, 1024, 0, stream>>>(bsum, bsx, nb);
    scan3<<<(n + 255) / 256, 256, 0, stream>>>(rp, cursor, bsx, deg, cnt, hist, n, e);
    fill<<<(e + 255) / 256, 256, 0, stream>>>(ei, ew, cursor, epack, flags, e, n);
    hscan<<<1, 256, 0, stream>>>(hist, hcur);
    sortk<<<nb, 1024, 0, stream>>>(cnt, hcur, order, n);

    gemm1_mfma<<<192, 256, 0, stream>>>(x, W1, deg, flags, (unsigned short*)G1, n);
    agg1<<<(n * 8 + 255) / 256, 256, 0, stream>>>(rp, epack, order, (const uint4*)G1,
                                                  deg, b1, flags, (uint4*)G2, n);
    agg2<<<(n * 8 + 255) / 256, 256, 0, stream>>>(rp, epack, order, (const uint4*)G2,
                                                  deg, (uint4*)G1, n);
    outgemm_mfma<<<192, 256, 0, stream>>>((const bf16*)G1, W2, b2, flags, d_out, n);
}